// Round 11
// baseline (687.494 us; speedup 1.0000x reference)
//
#include <hip/hip_runtime.h>
#include <math.h>

constexpr int IN_DIM = 1433;
constexpr int HID    = 16;
constexpr int OUTD   = 7;

// ---------- edge index access (int32 vs int64 auto-detect) ----------
__device__ __forceinline__ int edge_get(const int* __restrict__ ei, long long idx, int is64) {
    return is64 ? ei[2 * idx] : ei[idx];
}

// ---------- fused detect + init (deg=1, cnt=0) ----------
__global__ void k_detect_init(const int* __restrict__ ei, int* __restrict__ flag,
                              int* __restrict__ deg, int* __restrict__ cnt, int n) {
    int i = blockIdx.x * blockDim.x + threadIdx.x;
    if (i < n) { deg[i] = 1; cnt[i] = 0; }
    if (blockIdx.x == 0) {
        __shared__ int nzsh;
        if (threadIdx.x == 0) nzsh = 0;
        __syncthreads();
        int nz = 0;
        for (int j = threadIdx.x; j < 2048; j += blockDim.x)
            nz |= (ei[2 * j + 1] != 0) ? 1 : 0;
        if (nz) nzsh = 1;
        __syncthreads();
        if (threadIdx.x == 0) *flag = (nzsh == 0) ? 1 : 0;   // 1 => int64
    }
}

// ---------- pass 1: degree + CSR slot capture (R9-proven, standalone) ----------
__global__ void k_hist2(const int* __restrict__ ei, int E, const int* __restrict__ flag,
                        int* __restrict__ deg, int* __restrict__ cnt,
                        int* __restrict__ packed) {
    int e = blockIdx.x * blockDim.x + threadIdx.x;
    if (e >= E) return;
    int is64 = *flag;
    int s = edge_get(ei, e, is64);
    int d = edge_get(ei, (long long)E + e, is64);
    atomicAdd(&deg[s], 1);                       // fire-and-forget
    int slot = atomicAdd(&cnt[d], 1);            // returning
    packed[e] = (d << 14) | (slot & 16383);
}

// ---------- scan1 (+ fused deg_finish: dis[i] = rsqrt(deg[i]) in-place) ----------
__global__ __launch_bounds__(256) void k_scan1(const int* __restrict__ cnt,
                                               int* __restrict__ bsum,
                                               float* __restrict__ dis, int n) {
    __shared__ int sh[256];
    int t = threadIdx.x;
    int base = blockIdx.x * 1024 + t * 4;
    int s = 0;
    #pragma unroll
    for (int j = 0; j < 4; ++j) {
        int i = base + j;
        if (i < n) {
            s += cnt[i];
            int v = ((const int*)dis)[i];          // deg (int) aliased in dis buffer
            dis[i] = rsqrtf((float)v);
        }
    }
    sh[t] = s; __syncthreads();
    for (int o = 128; o > 0; o >>= 1) {
        if (t < o) sh[t] += sh[t + o];
        __syncthreads();
    }
    if (t == 0) bsum[blockIdx.x] = sh[0];
}

__global__ __launch_bounds__(256) void k_scan2(const int* __restrict__ bsum,
                                               int* __restrict__ boff,
                                               int* __restrict__ rp,
                                               int nb, int n, int E) {
    __shared__ int sh[256];
    int t = threadIdx.x;
    int v = (t < nb) ? bsum[t] : 0;
    sh[t] = v; __syncthreads();
    for (int o = 1; o < 256; o <<= 1) {
        int tmp = (t >= o) ? sh[t - o] : 0;
        __syncthreads();
        sh[t] += tmp;
        __syncthreads();
    }
    boff[t] = sh[t] - v;     // exclusive
    if (t == 0) rp[n] = E;   // total
}

__global__ __launch_bounds__(256) void k_scan3(const int* __restrict__ cnt,
                                               const int* __restrict__ boff,
                                               int* __restrict__ rp, int n) {
    __shared__ int sh[256];
    int t = threadIdx.x;
    int base = blockIdx.x * 1024 + t * 4;
    int c[4];
    int s = 0;
    #pragma unroll
    for (int j = 0; j < 4; ++j) {
        int i = base + j;
        c[j] = (i < n) ? cnt[i] : 0;
        s += c[j];
    }
    sh[t] = s; __syncthreads();
    for (int o = 1; o < 256; o <<= 1) {
        int tmp = (t >= o) ? sh[t - o] : 0;
        __syncthreads();
        sh[t] += tmp;
        __syncthreads();
    }
    int run = boff[blockIdx.x] + sh[t] - s;
    #pragma unroll
    for (int j = 0; j < 4; ++j) {
        int i = base + j;
        if (i < n) rp[i] = run;
        run += c[j];
    }
}

// ---------- place: csr[rp[d]+slot] = src  (NO atomics) ----------
__global__ void k_place(const int* __restrict__ ei, int E, const int* __restrict__ flag,
                        const int* __restrict__ packed, const int* __restrict__ rp,
                        int* __restrict__ csr) {
    int e = blockIdx.x * blockDim.x + threadIdx.x;
    if (e >= E) return;
    int is64 = *flag;
    int s  = edge_get(ei, e, is64);
    int p  = packed[e];
    int d  = p >> 14;
    int sl = p & 16383;
    csr[rp[d] + sl] = s;
}

// ---------- GEMM1 (R9-proven body, standalone): out = x @ W1 + b1 ----------
// scale_out=1: out = dis * (x@W1+b1)  (dis ready: graph build runs first)
// a1 != nullptr (fallback): also a1 = dis^2 * h (out holds raw h)
// BM=128 x 16, BK=32, 128 threads; b128 LDS reads; reg-staged prefetch.
__global__ __launch_bounds__(128) void k_gemm1(
        const float* __restrict__ x, const float* __restrict__ W1,
        const float* __restrict__ b1, const float* __restrict__ dis,
        float* __restrict__ h1, float* __restrict__ a1, int n, int scale_out) {
    constexpr int BK = 32, XST = 36;   // 144 B row stride (16B-aligned)
    __shared__ __align__(16) float xs[128 * XST];   // 18.4 KB
    __shared__ __align__(16) float wsm[BK * HID];   // 2 KB
    const int t    = threadIdx.x;
    const int c4   = t & 3;
    const int rq   = t >> 2;           // 0..31
    const int row0 = blockIdx.x * 128;

    float xreg[32];
    float wreg[4];
    float4 acc[4];
    #pragma unroll
    for (int j = 0; j < 4; ++j) acc[j] = make_float4(0.f, 0.f, 0.f, 0.f);

    auto issue = [&](int kt) {
        #pragma unroll
        for (int i = 0; i < 32; ++i) {
            int idx  = t + 128 * i;        // 0..4095
            int srow = idx >> 5;           // 0..127
            int scol = idx & 31;
            int gr   = row0 + srow;
            int col  = kt + scol;
            float v = 0.f;
            if (gr < n && col < IN_DIM) v = x[(long long)gr * IN_DIM + col];
            xreg[i] = v;
        }
        #pragma unroll
        for (int u = 0; u < 4; ++u) {
            int idx = t + 128 * u;         // 0..511
            int kk  = idx >> 4;
            wreg[u] = (kt + kk < IN_DIM) ? W1[(kt + kk) * HID + (idx & 15)] : 0.f;
        }
    };
    auto commit = [&]() {
        #pragma unroll
        for (int i = 0; i < 32; ++i) {
            int idx  = t + 128 * i;
            int srow = idx >> 5;
            int scol = idx & 31;
            xs[srow * XST + scol] = xreg[i];
        }
        #pragma unroll
        for (int u = 0; u < 4; ++u) wsm[t + 128 * u] = wreg[u];
    };

    const int nkt = (IN_DIM + BK - 1) / BK;   // 45
    issue(0);
    for (int it = 0; it < nkt; ++it) {
        commit();
        __syncthreads();
        if (it + 1 < nkt) issue((it + 1) * BK);   // overlaps with compute
        #pragma unroll
        for (int k4 = 0; k4 < BK / 4; ++k4) {
            int k = k4 * 4;
            float4 w0 = *(const float4*)&wsm[(k + 0) * HID + c4 * 4];
            float4 w1 = *(const float4*)&wsm[(k + 1) * HID + c4 * 4];
            float4 w2 = *(const float4*)&wsm[(k + 2) * HID + c4 * 4];
            float4 w3 = *(const float4*)&wsm[(k + 3) * HID + c4 * 4];
            #pragma unroll
            for (int j = 0; j < 4; ++j) {
                float4 xv = *(const float4*)&xs[(rq + 32 * j) * XST + k];
                acc[j].x += xv.x * w0.x + xv.y * w1.x + xv.z * w2.x + xv.w * w3.x;
                acc[j].y += xv.x * w0.y + xv.y * w1.y + xv.z * w2.y + xv.w * w3.y;
                acc[j].z += xv.x * w0.z + xv.y * w1.z + xv.z * w2.z + xv.w * w3.z;
                acc[j].w += xv.x * w0.w + xv.y * w1.w + xv.z * w2.w + xv.w * w3.w;
            }
        }
        __syncthreads();
    }

    float4 bv = *(const float4*)&b1[c4 * 4];
    #pragma unroll
    for (int j = 0; j < 4; ++j) {
        int gr = row0 + rq + 32 * j;
        if (gr < n) {
            float4 hv;
            hv.x = acc[j].x + bv.x;
            hv.y = acc[j].y + bv.y;
            hv.z = acc[j].z + bv.z;
            hv.w = acc[j].w + bv.w;
            if (scale_out) {
                float d = dis[gr];
                hv.x *= d; hv.y *= d; hv.z *= d; hv.w *= d;
            }
            *(float4*)&h1[(long long)gr * HID + c4 * 4] = hv;
            if (a1) {
                float d = dis[gr];
                float dd = d * d;
                float4 av;
                av.x = dd * hv.x; av.y = dd * hv.y; av.z = dd * hv.z; av.w = dd * hv.w;
                *(float4*)&a1[(long long)gr * HID + c4 * 4] = av;
            }
        }
    }
}

// ---------- scale (fallback only): out = dis[row]^2 * in ----------
__global__ void k_scale(const float* __restrict__ dis, const float* __restrict__ in,
                        float* __restrict__ out, int n, int squared) {
    int i = blockIdx.x * blockDim.x + threadIdx.x;   // one float4 per thread
    if (i >= n * 4) return;
    int row = i >> 2;
    float d = dis[row];
    if (squared) d *= d;
    float4 v = *(const float4*)&in[(long long)i * 4];
    v.x *= d; v.y *= d; v.z *= d; v.w *= d;
    *(float4*)&out[(long long)i * 4] = v;
}

// ---------- fused gather1 + gemm2 (pre-scaled inputs), 4-deep pipelined ----------
__global__ __launch_bounds__(256) void k_gather1f(
        const int* __restrict__ rp, const int* __restrict__ csr,
        const float* __restrict__ dis, const float* __restrict__ hs1,
        const float* __restrict__ W2, const float* __restrict__ b2,
        float* __restrict__ hs2, int n) {
    __shared__ float w2s[HID * OUTD];
    __shared__ float b2s[OUTD];
    int t = threadIdx.x;
    if (t < HID * OUTD) w2s[t] = W2[t];
    if (t < OUTD) b2s[t] = b2[t];
    __syncthreads();

    int tid  = blockIdx.x * blockDim.x + t;
    int node = tid >> 2;
    int q    = tid & 3;
    if (node >= n) return;

    float4 acc = *(const float4*)&hs1[(long long)node * HID + q * 4];  // self term

    int i = rp[node], end = rp[node + 1];
    for (; i + 4 <= end; i += 4) {
        int s0 = csr[i], s1 = csr[i + 1], s2 = csr[i + 2], s3 = csr[i + 3];
        float4 h0 = *(const float4*)&hs1[(long long)s0 * HID + q * 4];
        float4 h1 = *(const float4*)&hs1[(long long)s1 * HID + q * 4];
        float4 h2 = *(const float4*)&hs1[(long long)s2 * HID + q * 4];
        float4 h3 = *(const float4*)&hs1[(long long)s3 * HID + q * 4];
        acc.x += (h0.x + h1.x) + (h2.x + h3.x);
        acc.y += (h0.y + h1.y) + (h2.y + h3.y);
        acc.z += (h0.z + h1.z) + (h2.z + h3.z);
        acc.w += (h0.w + h1.w) + (h2.w + h3.w);
    }
    for (; i < end; ++i) {
        int s = csr[i];
        float4 h = *(const float4*)&hs1[(long long)s * HID + q * 4];
        acc.x += h.x; acc.y += h.y; acc.z += h.z; acc.w += h.w;
    }

    float dn = dis[node];
    float r0 = fmaxf(dn * acc.x, 0.f), r1 = fmaxf(dn * acc.y, 0.f);
    float r2 = fmaxf(dn * acc.z, 0.f), r3 = fmaxf(dn * acc.w, 0.f);
    float p[OUTD];
    #pragma unroll
    for (int j = 0; j < OUTD; ++j) {
        p[j] = r0 * w2s[(q * 4 + 0) * OUTD + j]
             + r1 * w2s[(q * 4 + 1) * OUTD + j]
             + r2 * w2s[(q * 4 + 2) * OUTD + j]
             + r3 * w2s[(q * 4 + 3) * OUTD + j];
    }
    #pragma unroll
    for (int j = 0; j < OUTD; ++j) {
        p[j] += __shfl_xor(p[j], 1, 4);
        p[j] += __shfl_xor(p[j], 2, 4);
    }
    hs2[(long long)node * OUTD + q] = dn * (p[q] + b2s[q]);
    if (q < 3) hs2[(long long)node * OUTD + q + 4] = dn * (p[q + 4] + b2s[q + 4]);
}

// ---------- gather2 + log_softmax fused (pre-scaled), 8-deep pipelined ----------
__global__ __launch_bounds__(256) void k_gather2(
        const int* __restrict__ rp, const int* __restrict__ csr,
        const float* __restrict__ dis, const float* __restrict__ hs2,
        float* __restrict__ out, int n) {
    int t = threadIdx.x;
    int node = blockIdx.x * 32 + (t >> 3);
    int q = t & 7;
    if (node >= n) return;
    float acc = -1e30f;
    if (q < OUTD) {
        acc = hs2[(long long)node * OUTD + q];   // self term
        int i = rp[node], end = rp[node + 1];
        for (; i + 8 <= end; i += 8) {
            int s0 = csr[i],     s1 = csr[i + 1], s2 = csr[i + 2], s3 = csr[i + 3];
            int s4 = csr[i + 4], s5 = csr[i + 5], s6 = csr[i + 6], s7 = csr[i + 7];
            float v0 = hs2[(long long)s0 * OUTD + q];
            float v1 = hs2[(long long)s1 * OUTD + q];
            float v2 = hs2[(long long)s2 * OUTD + q];
            float v3 = hs2[(long long)s3 * OUTD + q];
            float v4 = hs2[(long long)s4 * OUTD + q];
            float v5 = hs2[(long long)s5 * OUTD + q];
            float v6 = hs2[(long long)s6 * OUTD + q];
            float v7 = hs2[(long long)s7 * OUTD + q];
            acc += ((v0 + v1) + (v2 + v3)) + ((v4 + v5) + (v6 + v7));
        }
        for (; i < end; ++i) {
            int s = csr[i];
            acc += hs2[(long long)s * OUTD + q];
        }
        acc *= dis[node];
    }
    float m = acc;
    #pragma unroll
    for (int o = 1; o < 8; o <<= 1) m = fmaxf(m, __shfl_xor(m, o, 8));
    float ex = (q < OUTD) ? expf(acc - m) : 0.f;
    float ss = ex;
    #pragma unroll
    for (int o = 1; o < 8; o <<= 1) ss += __shfl_xor(ss, o, 8);
    if (q < OUTD) out[(long long)node * OUTD + q] = acc - m - logf(ss);
}

// ---------- fallback-only kernels (atomic path) ----------
__global__ void k_detect(const int* __restrict__ ei, int* __restrict__ flag) {
    __shared__ int nzsh;
    if (threadIdx.x == 0) nzsh = 0;
    __syncthreads();
    int nz = 0;
    for (int i = threadIdx.x; i < 2048; i += blockDim.x)
        nz |= (ei[2 * i + 1] != 0) ? 1 : 0;
    if (nz) nzsh = 1;
    __syncthreads();
    if (threadIdx.x == 0) *flag = (nzsh == 0) ? 1 : 0;
}

__global__ void k_deg_init(int* __restrict__ deg, int n) {
    int i = blockIdx.x * blockDim.x + threadIdx.x;
    if (i < n) deg[i] = 1;
}

__global__ void k_deg_count(const int* __restrict__ ei, int E,
                            const int* __restrict__ flag, int* __restrict__ deg) {
    int e = blockIdx.x * blockDim.x + threadIdx.x;
    if (e >= E) return;
    int is64 = *flag;
    int s = edge_get(ei, e, is64);
    atomicAdd(&deg[s], 1);
}

__global__ void k_deg_finish(float* __restrict__ dis, int n) {
    int i = blockIdx.x * blockDim.x + threadIdx.x;
    if (i < n) {
        int v = ((const int*)dis)[i];
        dis[i] = rsqrtf((float)v);
    }
}

__global__ void k_agg1(const int* __restrict__ ei, int E, const int* __restrict__ flag,
                       const float* __restrict__ dis, const float* __restrict__ h1,
                       float* __restrict__ a1) {
    long long tid = (long long)blockIdx.x * blockDim.x + threadIdx.x;
    int e = (int)(tid >> 2);
    int q = (int)(tid & 3);
    if (e >= E) return;
    int is64 = *flag;
    int s = edge_get(ei, e, is64);
    int d = edge_get(ei, (long long)E + e, is64);
    float nrm = dis[s] * dis[d];
    float4 v = *(const float4*)&h1[(long long)s * HID + q * 4];
    float* o = &a1[(long long)d * HID + q * 4];
    atomicAdd(o + 0, nrm * v.x);
    atomicAdd(o + 1, nrm * v.y);
    atomicAdd(o + 2, nrm * v.z);
    atomicAdd(o + 3, nrm * v.w);
}

__global__ __launch_bounds__(256) void k_gemm2(
        const float* __restrict__ a1, const float* __restrict__ W2,
        const float* __restrict__ b2, const float* __restrict__ dis,
        float* __restrict__ h2, float* __restrict__ a2, int n) {
    __shared__ float w2s[HID * OUTD];
    __shared__ float b2s[OUTD];
    int t = threadIdx.x;
    if (t < HID * OUTD) w2s[t] = W2[t];
    if (t < OUTD) b2s[t] = b2[t];
    __syncthreads();
    int r = blockIdx.x * blockDim.x + t;
    if (r >= n) return;
    float a[16];
    #pragma unroll
    for (int i = 0; i < 4; ++i) {
        float4 v = *(const float4*)&a1[(long long)r * HID + i * 4];
        a[4 * i + 0] = fmaxf(v.x, 0.f);
        a[4 * i + 1] = fmaxf(v.y, 0.f);
        a[4 * i + 2] = fmaxf(v.z, 0.f);
        a[4 * i + 3] = fmaxf(v.w, 0.f);
    }
    float dd = 0.f;
    if (a2) { float d = dis[r]; dd = d * d; }
    #pragma unroll
    for (int j = 0; j < OUTD; ++j) {
        float acc = b2s[j];
        #pragma unroll
        for (int k = 0; k < HID; ++k) acc += a[k] * w2s[k * OUTD + j];
        h2[(long long)r * OUTD + j] = acc;
        if (a2) a2[(long long)r * OUTD + j] = dd * acc;
    }
}

__global__ void k_agg2(const int* __restrict__ ei, int E, const int* __restrict__ flag,
                       const float* __restrict__ dis, const float* __restrict__ h2,
                       float* __restrict__ a2) {
    long long tid = (long long)blockIdx.x * blockDim.x + threadIdx.x;
    int e = (int)(tid >> 1);
    int q = (int)(tid & 1);
    if (e >= E) return;
    int is64 = *flag;
    int s = edge_get(ei, e, is64);
    int d = edge_get(ei, (long long)E + e, is64);
    float nrm = dis[s] * dis[d];
    int cnt = q ? 3 : 4;
    long long bs = (long long)s * OUTD + q * 4;
    long long bd = (long long)d * OUTD + q * 4;
    #pragma unroll
    for (int j = 0; j < 4; ++j)
        if (j < cnt) atomicAdd(&a2[bd + j], nrm * h2[bs + j]);
}

__global__ void k_lsm(const float* __restrict__ a2, float* __restrict__ out, int n) {
    int r = blockIdx.x * blockDim.x + threadIdx.x;
    if (r >= n) return;
    float v[OUTD];
    #pragma unroll
    for (int j = 0; j < OUTD; ++j) v[j] = a2[(long long)r * OUTD + j];
    float m = v[0];
    #pragma unroll
    for (int j = 1; j < OUTD; ++j) m = fmaxf(m, v[j]);
    float ssum = 0.f;
    #pragma unroll
    for (int j = 0; j < OUTD; ++j) ssum += expf(v[j] - m);
    float l = logf(ssum);
    #pragma unroll
    for (int j = 0; j < OUTD; ++j) out[(long long)r * OUTD + j] = v[j] - m - l;
}

extern "C" void kernel_launch(void* const* d_in, const int* in_sizes, int n_in,
                              void* d_out, int out_size, void* d_ws, size_t ws_size,
                              hipStream_t stream) {
    const float* x  = (const float*)d_in[0];
    const int*   ei = (const int*)d_in[1];
    const float* W1 = (const float*)d_in[2];
    const float* b1 = (const float*)d_in[3];
    const float* W2 = (const float*)d_in[4];
    const float* b2 = (const float*)d_in[5];
    float* out = (float*)d_out;

    const int N = in_sizes[0] / IN_DIM;   // 100000
    const int E = in_sizes[1] / 2;        // 3200000

    const int TPB = 256;
    const int gN  = (N + TPB - 1) / TPB;
    const int gE  = (E + TPB - 1) / TPB;
    const int gG1 = (N + 127) / 128;      // gemm blocks (128 threads, 128 rows)
    const int NB  = (N + 1023) / 1024;

    float* ws = (float*)d_ws;
    size_t o = 0;
    auto take = [&](size_t cnt) { size_t r = o; o += (cnt + 127) & ~(size_t)127; return r; };

    size_t off_dis  = take((size_t)N);
    size_t off_flag = take(64);
    size_t off_cnt  = take((size_t)N);
    size_t off_rp   = take((size_t)N + 1);
    size_t off_bs   = take(256);
    size_t off_bo   = take(256);
    size_t off_pk   = take((size_t)E);
    size_t off_csr  = take((size_t)E);
    size_t off_h1   = take((size_t)N * HID);
    size_t off_h2   = take((size_t)N * OUTD);
    size_t need_new = o * sizeof(float);

    if (ws_size >= need_new) {
        float* dis  = ws + off_dis;
        int*   degi = (int*)dis;
        int*   flag = (int*)(ws + off_flag);
        int*   cnt  = (int*)(ws + off_cnt);
        int*   rp   = (int*)(ws + off_rp);
        int*   bs   = (int*)(ws + off_bs);
        int*   bo   = (int*)(ws + off_bo);
        int*   pk   = (int*)(ws + off_pk);
        int*   csr  = (int*)(ws + off_csr);
        float* hs1  = ws + off_h1;   // gemm1 writes dis*h1 directly
        float* hs2  = ws + off_h2;

        // graph build first so dis is ready for gemm1's epilogue
        k_detect_init<<<gN, TPB, 0, stream>>>(ei, flag, degi, cnt, N);
        k_hist2<<<gE, TPB, 0, stream>>>(ei, E, flag, degi, cnt, pk);
        k_scan1<<<NB, 256, 0, stream>>>(cnt, bs, dis, N);   // + deg_finish fused
        k_scan2<<<1, 256, 0, stream>>>(bs, bo, rp, NB, N, E);
        k_scan3<<<NB, 256, 0, stream>>>(cnt, bo, rp, N);
        k_gemm1<<<gG1, 128, 0, stream>>>(x, W1, b1, dis, hs1, nullptr, N, 1);
        k_place<<<gE, TPB, 0, stream>>>(ei, E, flag, pk, rp, csr);
        k_gather1f<<<(int)(((long long)N * 4 + TPB - 1) / TPB), TPB, 0, stream>>>(
            rp, csr, dis, hs1, W2, b2, hs2, N);
        k_gather2<<<(N + 31) / 32, 256, 0, stream>>>(rp, csr, dis, hs2, out, N);
    } else {
        o = 0;
        size_t f_dis  = take((size_t)N);
        size_t f_flag = take(64);
        size_t f_h1   = take((size_t)N * HID);
        size_t f_a1   = take((size_t)N * HID);
        size_t f_h2   = take((size_t)N * OUTD);
        size_t f_a2   = take((size_t)N * OUTD);

        float* dis  = ws + f_dis;
        int*   degi = (int*)dis;
        int*   flag = (int*)(ws + f_flag);
        float* h1   = ws + f_h1;
        float* a1   = ws + f_a1;
        float* h2   = ws + f_h2;
        float* a2   = ws + f_a2;

        int g4E = (int)(((long long)4 * E + TPB - 1) / TPB);
        int g2E = (int)(((long long)2 * E + TPB - 1) / TPB);

        k_detect<<<1, 256, 0, stream>>>(ei, flag);
        k_deg_init<<<gN, TPB, 0, stream>>>(degi, N);
        k_deg_count<<<gE, TPB, 0, stream>>>(ei, E, flag, degi);
        k_deg_finish<<<gN, TPB, 0, stream>>>(dis, N);
        k_gemm1<<<gG1, 128, 0, stream>>>(x, W1, b1, dis, h1, a1, N, 0);
        k_agg1<<<g4E, TPB, 0, stream>>>(ei, E, flag, dis, h1, a1);
        k_gemm2<<<gN, TPB, 0, stream>>>(a1, W2, b2, dis, h2, a2, N);
        k_agg2<<<g2E, TPB, 0, stream>>>(ei, E, flag, dis, h2, a2);
        k_lsm<<<gN, TPB, 0, stream>>>(a2, out, N);
    }
}

// Round 12
// 643.900 us; speedup vs baseline: 1.0677x; 1.0677x over previous
//
#include <hip/hip_runtime.h>
#include <math.h>

constexpr int IN_DIM = 1433;
constexpr int HID    = 16;
constexpr int OUTD   = 7;

// ---------- edge index access (int32 vs int64 auto-detect) ----------
__device__ __forceinline__ int edge_get(const int* __restrict__ ei, long long idx, int is64) {
    return is64 ? ei[2 * idx] : ei[idx];
}

// ---------- fused detect + init (deg=1, cnt=0) ----------
__global__ void k_detect_init(const int* __restrict__ ei, int* __restrict__ flag,
                              int* __restrict__ deg, int* __restrict__ cnt, int n) {
    int i = blockIdx.x * blockDim.x + threadIdx.x;
    if (i < n) { deg[i] = 1; cnt[i] = 0; }
    if (blockIdx.x == 0) {
        __shared__ int nzsh;
        if (threadIdx.x == 0) nzsh = 0;
        __syncthreads();
        int nz = 0;
        for (int j = threadIdx.x; j < 2048; j += blockDim.x)
            nz |= (ei[2 * j + 1] != 0) ? 1 : 0;
        if (nz) nzsh = 1;
        __syncthreads();
        if (threadIdx.x == 0) *flag = (nzsh == 0) ? 1 : 0;   // 1 => int64
    }
}

// ---------- pass 1: degree + CSR slot capture ----------
__global__ void k_hist2(const int* __restrict__ ei, int E, const int* __restrict__ flag,
                        int* __restrict__ deg, int* __restrict__ cnt,
                        int* __restrict__ packed) {
    int e = blockIdx.x * blockDim.x + threadIdx.x;
    if (e >= E) return;
    int is64 = *flag;
    int s = edge_get(ei, e, is64);
    int d = edge_get(ei, (long long)E + e, is64);
    atomicAdd(&deg[s], 1);                       // fire-and-forget
    int slot = atomicAdd(&cnt[d], 1);            // returning
    packed[e] = (d << 14) | (slot & 16383);
}

// ---------- scan1 (+ fused deg_finish: dis[i] = rsqrt(deg[i]) in-place) ----------
__global__ __launch_bounds__(256) void k_scan1(const int* __restrict__ cnt,
                                               int* __restrict__ bsum,
                                               float* __restrict__ dis, int n) {
    __shared__ int sh[256];
    int t = threadIdx.x;
    int base = blockIdx.x * 1024 + t * 4;
    int s = 0;
    #pragma unroll
    for (int j = 0; j < 4; ++j) {
        int i = base + j;
        if (i < n) {
            s += cnt[i];
            int v = ((const int*)dis)[i];          // deg (int) aliased in dis buffer
            dis[i] = rsqrtf((float)v);
        }
    }
    sh[t] = s; __syncthreads();
    for (int o = 128; o > 0; o >>= 1) {
        if (t < o) sh[t] += sh[t + o];
        __syncthreads();
    }
    if (t == 0) bsum[blockIdx.x] = sh[0];
}

__global__ __launch_bounds__(256) void k_scan2(const int* __restrict__ bsum,
                                               int* __restrict__ boff,
                                               int* __restrict__ rp,
                                               int nb, int n, int E) {
    __shared__ int sh[256];
    int t = threadIdx.x;
    int v = (t < nb) ? bsum[t] : 0;
    sh[t] = v; __syncthreads();
    for (int o = 1; o < 256; o <<= 1) {
        int tmp = (t >= o) ? sh[t - o] : 0;
        __syncthreads();
        sh[t] += tmp;
        __syncthreads();
    }
    boff[t] = sh[t] - v;     // exclusive
    if (t == 0) rp[n] = E;   // total
}

__global__ __launch_bounds__(256) void k_scan3(const int* __restrict__ cnt,
                                               const int* __restrict__ boff,
                                               int* __restrict__ rp, int n) {
    __shared__ int sh[256];
    int t = threadIdx.x;
    int base = blockIdx.x * 1024 + t * 4;
    int c[4];
    int s = 0;
    #pragma unroll
    for (int j = 0; j < 4; ++j) {
        int i = base + j;
        c[j] = (i < n) ? cnt[i] : 0;
        s += c[j];
    }
    sh[t] = s; __syncthreads();
    for (int o = 1; o < 256; o <<= 1) {
        int tmp = (t >= o) ? sh[t - o] : 0;
        __syncthreads();
        sh[t] += tmp;
        __syncthreads();
    }
    int run = boff[blockIdx.x] + sh[t] - s;
    #pragma unroll
    for (int j = 0; j < 4; ++j) {
        int i = base + j;
        if (i < n) rp[i] = run;
        run += c[j];
    }
}

// ---------- place: csr[rp[d]+slot] = src  (NO atomics) ----------
__global__ void k_place(const int* __restrict__ ei, int E, const int* __restrict__ flag,
                        const int* __restrict__ packed, const int* __restrict__ rp,
                        int* __restrict__ csr) {
    int e = blockIdx.x * blockDim.x + threadIdx.x;
    if (e >= E) return;
    int is64 = *flag;
    int s  = edge_get(ei, e, is64);
    int p  = packed[e];
    int d  = p >> 14;
    int sl = p & 16383;
    csr[rp[d] + sl] = s;
}

// ---------- GEMM1: out = x @ W1 + b1 ----------
// scale_out=1: out = dis * (x@W1+b1). BM=128 x 16, BK=32, 128 threads.
// R11 body with b128 STAGING: x staged as 8 float4 loads + 8 ds_write_b128
// per thread per tile (was 32 b32); W1 as 1 float4 + 1 ds_write_b128 (was 4
// b32). Write cycles/wave/tile ~209 -> ~108 (LDS-issue-bound kernel).
// Reads/tiling/barriers unchanged (proven). fidx=row*36+chunk*4: 16B-aligned,
// banks 4*((row+chunk)%8) -> uniform 8 lanes/bank = m134 baseline pattern.
__global__ __launch_bounds__(128) void k_gemm1(
        const float* __restrict__ x, const float* __restrict__ W1,
        const float* __restrict__ b1, const float* __restrict__ dis,
        float* __restrict__ h1, float* __restrict__ a1, int n, int scale_out) {
    constexpr int BK = 32, XST = 36;   // 144 B row stride (16B-aligned)
    __shared__ __align__(16) float xs[128 * XST];   // 18.4 KB
    __shared__ __align__(16) float wsm[BK * HID];   // 2 KB
    const int t    = threadIdx.x;
    const int c4   = t & 3;
    const int rq   = t >> 2;           // 0..31
    const int row0 = blockIdx.x * 128;

    float4 xreg[8];
    float4 wreg;
    float4 acc[4];
    #pragma unroll
    for (int j = 0; j < 4; ++j) acc[j] = make_float4(0.f, 0.f, 0.f, 0.f);

    auto issue = [&](int kt) {
        #pragma unroll
        for (int i = 0; i < 8; ++i) {
            int idx4  = t + 128 * i;       // 0..1023 (16B chunks)
            int srow  = idx4 >> 3;         // 0..127
            int chunk = idx4 & 7;          // == t&7 (const per thread)
            int gr    = row0 + srow;
            int col   = kt + chunk * 4;
            float4 v = make_float4(0.f, 0.f, 0.f, 0.f);
            if (gr < n) {
                const float* p = x + (long long)gr * IN_DIM + col;
                if (col + 3 < IN_DIM) {
                    v = *(const float4*)p;     // 4B-aligned dwordx4 (proven R5/R8)
                } else if (col < IN_DIM) {
                    v.x = p[0];
                    if (col + 1 < IN_DIM) v.y = p[1];
                    if (col + 2 < IN_DIM) v.z = p[2];
                }
            }
            xreg[i] = v;
        }
        int kk = t >> 2;                   // 0..31
        int cc = (t & 3) * 4;
        wreg = (kt + kk < IN_DIM) ? *(const float4*)&W1[(kt + kk) * HID + cc]
                                  : make_float4(0.f, 0.f, 0.f, 0.f);
    };
    auto commit = [&]() {
        #pragma unroll
        for (int i = 0; i < 8; ++i) {
            int idx4  = t + 128 * i;
            int srow  = idx4 >> 3;
            int chunk = idx4 & 7;
            *(float4*)&xs[srow * XST + chunk * 4] = xreg[i];
        }
        *(float4*)&wsm[t * 4] = wreg;      // t*4 == (t>>2)*16 + (t&3)*4
    };

    const int nkt = (IN_DIM + BK - 1) / BK;   // 45
    issue(0);
    for (int it = 0; it < nkt; ++it) {
        commit();
        __syncthreads();
        if (it + 1 < nkt) issue((it + 1) * BK);   // overlaps with compute
        #pragma unroll
        for (int k4 = 0; k4 < BK / 4; ++k4) {
            int k = k4 * 4;
            float4 w0 = *(const float4*)&wsm[(k + 0) * HID + c4 * 4];
            float4 w1 = *(const float4*)&wsm[(k + 1) * HID + c4 * 4];
            float4 w2 = *(const float4*)&wsm[(k + 2) * HID + c4 * 4];
            float4 w3 = *(const float4*)&wsm[(k + 3) * HID + c4 * 4];
            #pragma unroll
            for (int j = 0; j < 4; ++j) {
                float4 xv = *(const float4*)&xs[(rq + 32 * j) * XST + k];
                acc[j].x += xv.x * w0.x + xv.y * w1.x + xv.z * w2.x + xv.w * w3.x;
                acc[j].y += xv.x * w0.y + xv.y * w1.y + xv.z * w2.y + xv.w * w3.y;
                acc[j].z += xv.x * w0.z + xv.y * w1.z + xv.z * w2.z + xv.w * w3.z;
                acc[j].w += xv.x * w0.w + xv.y * w1.w + xv.z * w2.w + xv.w * w3.w;
            }
        }
        __syncthreads();
    }

    float4 bv = *(const float4*)&b1[c4 * 4];
    #pragma unroll
    for (int j = 0; j < 4; ++j) {
        int gr = row0 + rq + 32 * j;
        if (gr < n) {
            float4 hv;
            hv.x = acc[j].x + bv.x;
            hv.y = acc[j].y + bv.y;
            hv.z = acc[j].z + bv.z;
            hv.w = acc[j].w + bv.w;
            if (scale_out) {
                float d = dis[gr];
                hv.x *= d; hv.y *= d; hv.z *= d; hv.w *= d;
            }
            *(float4*)&h1[(long long)gr * HID + c4 * 4] = hv;
            if (a1) {
                float d = dis[gr];
                float dd = d * d;
                float4 av;
                av.x = dd * hv.x; av.y = dd * hv.y; av.z = dd * hv.z; av.w = dd * hv.w;
                *(float4*)&a1[(long long)gr * HID + c4 * 4] = av;
            }
        }
    }
}

// ---------- scale (fallback only): out = dis[row]^2 * in ----------
__global__ void k_scale(const float* __restrict__ dis, const float* __restrict__ in,
                        float* __restrict__ out, int n, int squared) {
    int i = blockIdx.x * blockDim.x + threadIdx.x;   // one float4 per thread
    if (i >= n * 4) return;
    int row = i >> 2;
    float d = dis[row];
    if (squared) d *= d;
    float4 v = *(const float4*)&in[(long long)i * 4];
    v.x *= d; v.y *= d; v.z *= d; v.w *= d;
    *(float4*)&out[(long long)i * 4] = v;
}

// ---------- fused gather1 + gemm2 (pre-scaled inputs), 4-deep pipelined ----------
__global__ __launch_bounds__(256) void k_gather1f(
        const int* __restrict__ rp, const int* __restrict__ csr,
        const float* __restrict__ dis, const float* __restrict__ hs1,
        const float* __restrict__ W2, const float* __restrict__ b2,
        float* __restrict__ hs2, int n) {
    __shared__ float w2s[HID * OUTD];
    __shared__ float b2s[OUTD];
    int t = threadIdx.x;
    if (t < HID * OUTD) w2s[t] = W2[t];
    if (t < OUTD) b2s[t] = b2[t];
    __syncthreads();

    int tid  = blockIdx.x * blockDim.x + t;
    int node = tid >> 2;
    int q    = tid & 3;
    if (node >= n) return;

    float4 acc = *(const float4*)&hs1[(long long)node * HID + q * 4];  // self term

    int i = rp[node], end = rp[node + 1];
    for (; i + 4 <= end; i += 4) {
        int s0 = csr[i], s1 = csr[i + 1], s2 = csr[i + 2], s3 = csr[i + 3];
        float4 h0 = *(const float4*)&hs1[(long long)s0 * HID + q * 4];
        float4 h1 = *(const float4*)&hs1[(long long)s1 * HID + q * 4];
        float4 h2 = *(const float4*)&hs1[(long long)s2 * HID + q * 4];
        float4 h3 = *(const float4*)&hs1[(long long)s3 * HID + q * 4];
        acc.x += (h0.x + h1.x) + (h2.x + h3.x);
        acc.y += (h0.y + h1.y) + (h2.y + h3.y);
        acc.z += (h0.z + h1.z) + (h2.z + h3.z);
        acc.w += (h0.w + h1.w) + (h2.w + h3.w);
    }
    for (; i < end; ++i) {
        int s = csr[i];
        float4 h = *(const float4*)&hs1[(long long)s * HID + q * 4];
        acc.x += h.x; acc.y += h.y; acc.z += h.z; acc.w += h.w;
    }

    float dn = dis[node];
    float r0 = fmaxf(dn * acc.x, 0.f), r1 = fmaxf(dn * acc.y, 0.f);
    float r2 = fmaxf(dn * acc.z, 0.f), r3 = fmaxf(dn * acc.w, 0.f);
    float p[OUTD];
    #pragma unroll
    for (int j = 0; j < OUTD; ++j) {
        p[j] = r0 * w2s[(q * 4 + 0) * OUTD + j]
             + r1 * w2s[(q * 4 + 1) * OUTD + j]
             + r2 * w2s[(q * 4 + 2) * OUTD + j]
             + r3 * w2s[(q * 4 + 3) * OUTD + j];
    }
    #pragma unroll
    for (int j = 0; j < OUTD; ++j) {
        p[j] += __shfl_xor(p[j], 1, 4);
        p[j] += __shfl_xor(p[j], 2, 4);
    }
    hs2[(long long)node * OUTD + q] = dn * (p[q] + b2s[q]);
    if (q < 3) hs2[(long long)node * OUTD + q + 4] = dn * (p[q + 4] + b2s[q + 4]);
}

// ---------- gather2 + log_softmax fused (pre-scaled), 8-deep pipelined ----------
__global__ __launch_bounds__(256) void k_gather2(
        const int* __restrict__ rp, const int* __restrict__ csr,
        const float* __restrict__ dis, const float* __restrict__ hs2,
        float* __restrict__ out, int n) {
    int t = threadIdx.x;
    int node = blockIdx.x * 32 + (t >> 3);
    int q = t & 7;
    if (node >= n) return;
    float acc = -1e30f;
    if (q < OUTD) {
        acc = hs2[(long long)node * OUTD + q];   // self term
        int i = rp[node], end = rp[node + 1];
        for (; i + 8 <= end; i += 8) {
            int s0 = csr[i],     s1 = csr[i + 1], s2 = csr[i + 2], s3 = csr[i + 3];
            int s4 = csr[i + 4], s5 = csr[i + 5], s6 = csr[i + 6], s7 = csr[i + 7];
            float v0 = hs2[(long long)s0 * OUTD + q];
            float v1 = hs2[(long long)s1 * OUTD + q];
            float v2 = hs2[(long long)s2 * OUTD + q];
            float v3 = hs2[(long long)s3 * OUTD + q];
            float v4 = hs2[(long long)s4 * OUTD + q];
            float v5 = hs2[(long long)s5 * OUTD + q];
            float v6 = hs2[(long long)s6 * OUTD + q];
            float v7 = hs2[(long long)s7 * OUTD + q];
            acc += ((v0 + v1) + (v2 + v3)) + ((v4 + v5) + (v6 + v7));
        }
        for (; i < end; ++i) {
            int s = csr[i];
            acc += hs2[(long long)s * OUTD + q];
        }
        acc *= dis[node];
    }
    float m = acc;
    #pragma unroll
    for (int o = 1; o < 8; o <<= 1) m = fmaxf(m, __shfl_xor(m, o, 8));
    float ex = (q < OUTD) ? expf(acc - m) : 0.f;
    float ss = ex;
    #pragma unroll
    for (int o = 1; o < 8; o <<= 1) ss += __shfl_xor(ss, o, 8);
    if (q < OUTD) out[(long long)node * OUTD + q] = acc - m - logf(ss);
}

// ---------- fallback-only kernels (atomic path) ----------
__global__ void k_detect(const int* __restrict__ ei, int* __restrict__ flag) {
    __shared__ int nzsh;
    if (threadIdx.x == 0) nzsh = 0;
    __syncthreads();
    int nz = 0;
    for (int i = threadIdx.x; i < 2048; i += blockDim.x)
        nz |= (ei[2 * i + 1] != 0) ? 1 : 0;
    if (nz) nzsh = 1;
    __syncthreads();
    if (threadIdx.x == 0) *flag = (nzsh == 0) ? 1 : 0;
}

__global__ void k_deg_init(int* __restrict__ deg, int n) {
    int i = blockIdx.x * blockDim.x + threadIdx.x;
    if (i < n) deg[i] = 1;
}

__global__ void k_deg_count(const int* __restrict__ ei, int E,
                            const int* __restrict__ flag, int* __restrict__ deg) {
    int e = blockIdx.x * blockDim.x + threadIdx.x;
    if (e >= E) return;
    int is64 = *flag;
    int s = edge_get(ei, e, is64);
    atomicAdd(&deg[s], 1);
}

__global__ void k_deg_finish(float* __restrict__ dis, int n) {
    int i = blockIdx.x * blockDim.x + threadIdx.x;
    if (i < n) {
        int v = ((const int*)dis)[i];
        dis[i] = rsqrtf((float)v);
    }
}

__global__ void k_agg1(const int* __restrict__ ei, int E, const int* __restrict__ flag,
                       const float* __restrict__ dis, const float* __restrict__ h1,
                       float* __restrict__ a1) {
    long long tid = (long long)blockIdx.x * blockDim.x + threadIdx.x;
    int e = (int)(tid >> 2);
    int q = (int)(tid & 3);
    if (e >= E) return;
    int is64 = *flag;
    int s = edge_get(ei, e, is64);
    int d = edge_get(ei, (long long)E + e, is64);
    float nrm = dis[s] * dis[d];
    float4 v = *(const float4*)&h1[(long long)s * HID + q * 4];
    float* o = &a1[(long long)d * HID + q * 4];
    atomicAdd(o + 0, nrm * v.x);
    atomicAdd(o + 1, nrm * v.y);
    atomicAdd(o + 2, nrm * v.z);
    atomicAdd(o + 3, nrm * v.w);
}

__global__ __launch_bounds__(256) void k_gemm2(
        const float* __restrict__ a1, const float* __restrict__ W2,
        const float* __restrict__ b2, const float* __restrict__ dis,
        float* __restrict__ h2, float* __restrict__ a2, int n) {
    __shared__ float w2s[HID * OUTD];
    __shared__ float b2s[OUTD];
    int t = threadIdx.x;
    if (t < HID * OUTD) w2s[t] = W2[t];
    if (t < OUTD) b2s[t] = b2[t];
    __syncthreads();
    int r = blockIdx.x * blockDim.x + t;
    if (r >= n) return;
    float a[16];
    #pragma unroll
    for (int i = 0; i < 4; ++i) {
        float4 v = *(const float4*)&a1[(long long)r * HID + i * 4];
        a[4 * i + 0] = fmaxf(v.x, 0.f);
        a[4 * i + 1] = fmaxf(v.y, 0.f);
        a[4 * i + 2] = fmaxf(v.z, 0.f);
        a[4 * i + 3] = fmaxf(v.w, 0.f);
    }
    float dd = 0.f;
    if (a2) { float d = dis[r]; dd = d * d; }
    #pragma unroll
    for (int j = 0; j < OUTD; ++j) {
        float acc = b2s[j];
        #pragma unroll
        for (int k = 0; k < HID; ++k) acc += a[k] * w2s[k * OUTD + j];
        h2[(long long)r * OUTD + j] = acc;
        if (a2) a2[(long long)r * OUTD + j] = dd * acc;
    }
}

__global__ void k_agg2(const int* __restrict__ ei, int E, const int* __restrict__ flag,
                       const float* __restrict__ dis, const float* __restrict__ h2,
                       float* __restrict__ a2) {
    long long tid = (long long)blockIdx.x * blockDim.x + threadIdx.x;
    int e = (int)(tid >> 1);
    int q = (int)(tid & 1);
    if (e >= E) return;
    int is64 = *flag;
    int s = edge_get(ei, e, is64);
    int d = edge_get(ei, (long long)E + e, is64);
    float nrm = dis[s] * dis[d];
    int cnt = q ? 3 : 4;
    long long bs = (long long)s * OUTD + q * 4;
    long long bd = (long long)d * OUTD + q * 4;
    #pragma unroll
    for (int j = 0; j < 4; ++j)
        if (j < cnt) atomicAdd(&a2[bd + j], nrm * h2[bs + j]);
}

__global__ void k_lsm(const float* __restrict__ a2, float* __restrict__ out, int n) {
    int r = blockIdx.x * blockDim.x + threadIdx.x;
    if (r >= n) return;
    float v[OUTD];
    #pragma unroll
    for (int j = 0; j < OUTD; ++j) v[j] = a2[(long long)r * OUTD + j];
    float m = v[0];
    #pragma unroll
    for (int j = 1; j < OUTD; ++j) m = fmaxf(m, v[j]);
    float ssum = 0.f;
    #pragma unroll
    for (int j = 0; j < OUTD; ++j) ssum += expf(v[j] - m);
    float l = logf(ssum);
    #pragma unroll
    for (int j = 0; j < OUTD; ++j) out[(long long)r * OUTD + j] = v[j] - m - l;
}

extern "C" void kernel_launch(void* const* d_in, const int* in_sizes, int n_in,
                              void* d_out, int out_size, void* d_ws, size_t ws_size,
                              hipStream_t stream) {
    const float* x  = (const float*)d_in[0];
    const int*   ei = (const int*)d_in[1];
    const float* W1 = (const float*)d_in[2];
    const float* b1 = (const float*)d_in[3];
    const float* W2 = (const float*)d_in[4];
    const float* b2 = (const float*)d_in[5];
    float* out = (float*)d_out;

    const int N = in_sizes[0] / IN_DIM;   // 100000
    const int E = in_sizes[1] / 2;        // 3200000

    const int TPB = 256;
    const int gN  = (N + TPB - 1) / TPB;
    const int gE  = (E + TPB - 1) / TPB;
    const int gG1 = (N + 127) / 128;      // gemm blocks (128 threads, 128 rows)
    const int NB  = (N + 1023) / 1024;

    float* ws = (float*)d_ws;
    size_t o = 0;
    auto take = [&](size_t cnt) { size_t r = o; o += (cnt + 127) & ~(size_t)127; return r; };

    size_t off_dis  = take((size_t)N);
    size_t off_flag = take(64);
    size_t off_cnt  = take((size_t)N);
    size_t off_rp   = take((size_t)N + 1);
    size_t off_bs   = take(256);
    size_t off_bo   = take(256);
    size_t off_pk   = take((size_t)E);
    size_t off_csr  = take((size_t)E);
    size_t off_h1   = take((size_t)N * HID);
    size_t off_h2   = take((size_t)N * OUTD);
    size_t need_new = o * sizeof(float);

    if (ws_size >= need_new) {
        float* dis  = ws + off_dis;
        int*   degi = (int*)dis;
        int*   flag = (int*)(ws + off_flag);
        int*   cnt  = (int*)(ws + off_cnt);
        int*   rp   = (int*)(ws + off_rp);
        int*   bs   = (int*)(ws + off_bs);
        int*   bo   = (int*)(ws + off_bo);
        int*   pk   = (int*)(ws + off_pk);
        int*   csr  = (int*)(ws + off_csr);
        float* hs1  = ws + off_h1;   // gemm1 writes dis*h1 directly
        float* hs2  = ws + off_h2;

        // graph build first so dis is ready for gemm1's epilogue
        k_detect_init<<<gN, TPB, 0, stream>>>(ei, flag, degi, cnt, N);
        k_hist2<<<gE, TPB, 0, stream>>>(ei, E, flag, degi, cnt, pk);
        k_scan1<<<NB, 256, 0, stream>>>(cnt, bs, dis, N);   // + deg_finish fused
        k_scan2<<<1, 256, 0, stream>>>(bs, bo, rp, NB, N, E);
        k_scan3<<<NB, 256, 0, stream>>>(cnt, bo, rp, N);
        k_gemm1<<<gG1, 128, 0, stream>>>(x, W1, b1, dis, hs1, nullptr, N, 1);
        k_place<<<gE, TPB, 0, stream>>>(ei, E, flag, pk, rp, csr);
        k_gather1f<<<(int)(((long long)N * 4 + TPB - 1) / TPB), TPB, 0, stream>>>(
            rp, csr, dis, hs1, W2, b2, hs2, N);
        k_gather2<<<(N + 31) / 32, 256, 0, stream>>>(rp, csr, dis, hs2, out, N);
    } else {
        o = 0;
        size_t f_dis  = take((size_t)N);
        size_t f_flag = take(64);
        size_t f_h1   = take((size_t)N * HID);
        size_t f_a1   = take((size_t)N * HID);
        size_t f_h2   = take((size_t)N * OUTD);
        size_t f_a2   = take((size_t)N * OUTD);

        float* dis  = ws + f_dis;
        int*   degi = (int*)dis;
        int*   flag = (int*)(ws + f_flag);
        float* h1   = ws + f_h1;
        float* a1   = ws + f_a1;
        float* h2   = ws + f_h2;
        float* a2   = ws + f_a2;

        int g4E = (int)(((long long)4 * E + TPB - 1) / TPB);
        int g2E = (int)(((long long)2 * E + TPB - 1) / TPB);

        k_detect<<<1, 256, 0, stream>>>(ei, flag);
        k_deg_init<<<gN, TPB, 0, stream>>>(degi, N);
        k_deg_count<<<gE, TPB, 0, stream>>>(ei, E, flag, degi);
        k_deg_finish<<<gN, TPB, 0, stream>>>(dis, N);
        k_gemm1<<<gG1, 128, 0, stream>>>(x, W1, b1, dis, h1, a1, N, 0);
        k_agg1<<<g4E, TPB, 0, stream>>>(ei, E, flag, dis, h1, a1);
        k_gemm2<<<gN, TPB, 0, stream>>>(a1, W2, b2, dis, h2, a2, N);
        k_agg2<<<g2E, TPB, 0, stream>>>(ei, E, flag, dis, h2, a2);
        k_lsm<<<gN, TPB, 0, stream>>>(a2, out, N);
    }
}